// Round 8
// baseline (255.091 us; speedup 1.0000x reference)
//
#include <hip/hip_runtime.h>

#define NN 100000
#define NH 50000         // src-half split point
#define NE 1600000
#define IC 128
#define HID 32
#define NB 782           // buckets of 128 nodes
#define BCAP 2560        // padded bucket capacity
#define EB 4096          // edges per binning block
#define NBA 391          // ceil(NE/EB)
#define NPJ 3125         // ceil(NN/32) proj blocks (32-node tile)

typedef unsigned short ushort_t;

__device__ __forceinline__ ushort_t f2bf(float x) {
    unsigned u = __float_as_uint(x);
    unsigned r = (u + 0x7fffu + ((u >> 16) & 1u)) >> 16;   // RNE
    return (ushort_t)r;
}
__device__ __forceinline__ float bf2f(ushort_t b) {
    return __uint_as_float(((unsigned)b) << 16);
}

__device__ __forceinline__ int edge_at(const void* ei, int i64f, long long idx) {
    return i64f ? (int)((const long long*)ei)[idx] : ((const int*)ei)[idx];
}

// ---------------- setup: detect dtype + precompute folded weights + zero cursors ----------------
__global__ __launch_bounds__(1024) void setup_kernel(const void* ei,
                                                     const float* __restrict__ w1b, const float* __restrict__ b1b,
                                                     const float* __restrict__ w2a, const float* __restrict__ w2b,
                                                     const float* __restrict__ b2b, const float* __restrict__ w3,
                                                     int* flag, int* gcursor,
                                                     float* Wc, float* bc1, float* wc2, float* c0) {
    int t = threadIdx.x;
    if (blockIdx.x == 1) {
        if (t < NB) gcursor[t] = 0;
        return;
    }
    if (t < 64) {
        const long long* p = (const long long*)ei;
        long long v = p[t];
        unsigned long long bad = __ballot(v < 0 || v >= NN);
        if (t == 0) *flag = (bad == 0ull) ? 1 : 0;
    }
    int k = t >> 5, j = t & 31;
    float acc = 0.f;
    for (int m = 0; m < HID; m++) acc += w1b[k * HID + m] * w2a[m * HID + j];
    Wc[k * HID + j] = acc;
    if (t < 32) {
        float a = 0.f;
        for (int m = 0; m < HID; m++) a += b1b[m] * w2a[m * HID + t];
        bc1[t] = a;
    } else if (t < 64) {
        int kk = t - 32;
        float a = 0.f;
        for (int jj = 0; jj < HID; jj++) a += w2b[kk * HID + jj] * w3[jj];
        wc2[kk] = a;
    } else if (t == 64) {
        float a = 0.f;
        for (int jj = 0; jj < HID; jj++) a += b2b[jj] * w3[jj];
        *c0 = a;
    }
}

// ---------------- proj (32-node tile) + binscatter (LDS-lean re-read) merged ----------------
union SMU {
    struct { float xs[32 * 132]; float ws[IC * HID]; } pj;  // 16,896 + 16,384 = 33,280 B
    struct { int h[NB]; int lcur[NB]; } bs;                 //  6,256 B
};

__global__ __launch_bounds__(256) void proj_bin_kernel(const float* __restrict__ x,
                                                       const float* __restrict__ w1a,
                                                       ushort_t* __restrict__ y1,
                                                       const void* ei, const int* flag,
                                                       int* gcursor,
                                                       unsigned int* __restrict__ binned) {
    __shared__ SMU sm;
    int t = threadIdx.x;

    if (blockIdx.x < NPJ) {
        // ---- proj: y1 = bf16(x @ w1a). 32 nodes/block, LDS 33.3 KB -> 4 blocks/CU ----
        int base = blockIdx.x * 32;          // NPJ*32 == NN exactly
        #pragma unroll
        for (int i = 0; i < 16; i++) sm.pj.ws[i * 256 + t] = w1a[i * 256 + t];
        const float4* xg = (const float4*)x;
        #pragma unroll
        for (int i = 0; i < 4; i++) {
            int fi = i * 256 + t;            // 0..1023
            int row = fi >> 5;               // 0..31
            int kq = fi & 31;
            float4 v = xg[(size_t)(base + row) * 32 + kq];
            *(float4*)&sm.pj.xs[row * 132 + kq * 4] = v;
        }
        __syncthreads();

        int ng = t >> 3;        // node 0..31
        int fg = t & 7;         // col quad
        int j0 = fg * 4;
        float4 a0 = make_float4(0.f, 0.f, 0.f, 0.f);
        #pragma unroll 8
        for (int k = 0; k < IC; k++) {
            float x0 = sm.pj.xs[ng * 132 + k];
            float4 w = *(const float4*)&sm.pj.ws[k * HID + j0];
            a0.x += x0 * w.x; a0.y += x0 * w.y; a0.z += x0 * w.z; a0.w += x0 * w.w;
        }
        ushort4 p0;
        p0.x = f2bf(a0.x); p0.y = f2bf(a0.y); p0.z = f2bf(a0.z); p0.w = f2bf(a0.w);
        *(ushort4*)&y1[(size_t)(base + ng) * 32 + j0] = p0;
    } else {
        // ---- binscatter: histogram + reserve + scatter, edges re-read from L2 ----
        int bb = blockIdx.x - NPJ;
        for (int b = t; b < NB; b += 256) sm.bs.h[b] = 0;
        __syncthreads();
        int i64f = *flag;
        long long ebase = (long long)bb * EB;
        for (int i = t; i < EB; i += 256) {
            long long e = ebase + i;
            if (e < NE) {
                int d = edge_at(ei, i64f, NE + e);
                atomicAdd(&sm.bs.h[d >> 7], 1);
            }
        }
        __syncthreads();
        for (int b = t; b < NB; b += 256)
            sm.bs.lcur[b] = sm.bs.h[b] ? atomicAdd(&gcursor[b], sm.bs.h[b]) : 0;
        __syncthreads();
        for (int i = t; i < EB; i += 256) {
            long long e = ebase + i;
            if (e < NE) {
                int s = edge_at(ei, i64f, e);
                int d = edge_at(ei, i64f, NE + e);
                int b = d >> 7;
                int pos = atomicAdd(&sm.bs.lcur[b], 1);
                binned[(size_t)b * BCAP + pos] = ((unsigned)s << 7) | (unsigned)(d & 127);
            }
        }
    }
}

// ---------------- per-bucket CSR with (node, src-half) ordering ----------------
__global__ __launch_bounds__(256) void bucket_csr_kernel(const unsigned int* __restrict__ binned,
                                                         const int* __restrict__ gcursor,
                                                         int* __restrict__ rowbeg,
                                                         int* __restrict__ rowmid,
                                                         int* __restrict__ rowend,
                                                         int* __restrict__ esrc) {
    __shared__ int cnt[256];
    __shared__ int sc[256];
    __shared__ int cur[256];
    int t = threadIdx.x;
    int b = blockIdx.x;
    int n = gcursor[b];
    int bbase = b * BCAP;
    cnt[t] = 0;
    __syncthreads();
    for (int p = t; p < n; p += 256) {
        unsigned w = binned[bbase + p];
        int idx = ((w & 127) << 1) | (((w >> 7) >= NH) ? 1 : 0);
        atomicAdd(&cnt[idx], 1);
    }
    __syncthreads();
    sc[t] = cnt[t];
    __syncthreads();
    for (int off = 1; off < 256; off <<= 1) {
        int a = (t >= off) ? sc[t - off] : 0;
        __syncthreads();
        sc[t] += a;
        __syncthreads();
    }
    cur[t] = sc[t] - cnt[t];   // exclusive
    __syncthreads();
    if (t < 128) {
        int gn = (b << 7) + t;
        if (gn < NN) {
            rowbeg[gn] = bbase + cur[2 * t];
            rowmid[gn] = bbase + cur[2 * t + 1];
            rowend[gn] = bbase + cur[2 * t + 1] + cnt[2 * t + 1];
        }
    }
    __syncthreads();           // rowptr reads must precede cur mutation
    for (int p = t; p < n; p += 256) {
        unsigned w = binned[bbase + p];
        int src = w >> 7;
        int idx = ((w & 127) << 1) | ((src >= NH) ? 1 : 0);
        int pos = bbase + atomicAdd(&cur[idx], 1);
        esrc[pos] = src;
    }
}

// ---------------- agg_half: gather-sum one src-half (L2-resident 3.2MB window) ----------------
// one wave per node; 8 groups of 8 lanes; lane loads ushort4 (8B) => 1 line/edge.
// partial written bf16 via nontemporal store (don't evict y from L2).
__global__ __launch_bounds__(256) void agg_half_kernel(const ushort_t* __restrict__ y,
                                                       const int* __restrict__ rb,
                                                       const int* __restrict__ re,
                                                       const int* __restrict__ esrc,
                                                       ushort_t* __restrict__ part) {
    int t = threadIdx.x;
    int wv = t >> 6;
    int lane = t & 63;
    int grp = lane >> 3;      // 0..7
    int l = lane & 7;         // features 4l..4l+3
    int n = blockIdx.x * 4 + wv;       // NN divisible by 4

    int beg = rb[n], end = re[n];
    float ax = 0.f, ay = 0.f, az = 0.f, aw = 0.f;
    float bx = 0.f, by = 0.f, bz = 0.f, bw = 0.f;
    int p = beg + grp;
    for (; p + 8 < end; p += 16) {
        int s0 = __builtin_nontemporal_load(&esrc[p]);
        int s1 = __builtin_nontemporal_load(&esrc[p + 8]);
        ushort4 u0 = *(const ushort4*)&y[(size_t)s0 * 32 + l * 4];
        ushort4 u1 = *(const ushort4*)&y[(size_t)s1 * 32 + l * 4];
        ax += bf2f(u0.x); ay += bf2f(u0.y); az += bf2f(u0.z); aw += bf2f(u0.w);
        bx += bf2f(u1.x); by += bf2f(u1.y); bz += bf2f(u1.z); bw += bf2f(u1.w);
    }
    if (p < end) {
        int s0 = __builtin_nontemporal_load(&esrc[p]);
        ushort4 u0 = *(const ushort4*)&y[(size_t)s0 * 32 + l * 4];
        ax += bf2f(u0.x); ay += bf2f(u0.y); az += bf2f(u0.z); aw += bf2f(u0.w);
    }
    float vx = ax + bx, vy = ay + by, vz = az + bz, vw = aw + bw;
    vx += __shfl_xor(vx, 8, 64);  vy += __shfl_xor(vy, 8, 64);
    vz += __shfl_xor(vz, 8, 64);  vw += __shfl_xor(vw, 8, 64);
    vx += __shfl_xor(vx, 16, 64); vy += __shfl_xor(vy, 16, 64);
    vz += __shfl_xor(vz, 16, 64); vw += __shfl_xor(vw, 16, 64);
    vx += __shfl_xor(vx, 32, 64); vy += __shfl_xor(vy, 32, 64);
    vz += __shfl_xor(vz, 32, 64); vw += __shfl_xor(vw, 32, 64);
    if (lane < 8) {
        unsigned long long pk = (unsigned long long)f2bf(vx)
                              | ((unsigned long long)f2bf(vy) << 16)
                              | ((unsigned long long)f2bf(vz) << 32)
                              | ((unsigned long long)f2bf(vw) << 48);
        __builtin_nontemporal_store(pk, (unsigned long long*)&part[(size_t)n * 32 + l * 4]);
    }
}

// ---------------- mlp1: y2 = relu(p0+p1+self + b1a) @ Wc + bc1 -> bf16 ----------------
__global__ __launch_bounds__(256) void mlp1_kernel(const ushort_t* __restrict__ p0,
                                                   const ushort_t* __restrict__ p1,
                                                   const ushort_t* __restrict__ yself,
                                                   const float* __restrict__ b1a,
                                                   const float* __restrict__ Wc,
                                                   const float* __restrict__ bc1,
                                                   ushort_t* __restrict__ y2) {
    __shared__ float Wl[HID * HID];
    __shared__ float b1l[HID];
    __shared__ float bcl[HID];
    int t = threadIdx.x;
    #pragma unroll
    for (int i = 0; i < 4; i++) Wl[i * 256 + t] = Wc[i * 256 + t];
    if (t < HID) { b1l[t] = b1a[t]; bcl[t] = bc1[t]; }
    __syncthreads();

    int sub = t >> 5;
    int f = t & 31;
    int n = blockIdx.x * 8 + sub;      // NN divisible by 8
    size_t ix = (size_t)n * 32 + f;

    float u = bf2f(p0[ix]) + bf2f(p1[ix]) + bf2f(yself[ix]) + b1l[f];
    u = u > 0.f ? u : 0.f;
    float o = bcl[f];
    #pragma unroll
    for (int k = 0; k < HID; k++)
        o += __shfl(u, k, 32) * Wl[k * HID + f];

    y2[ix] = f2bf(o);
}

// ---------------- mlp2: s = relu(p0+p1+self + b2a) . wc2 + c0 ----------------
__global__ __launch_bounds__(256) void mlp2_kernel(const ushort_t* __restrict__ p0,
                                                   const ushort_t* __restrict__ p1,
                                                   const ushort_t* __restrict__ yself,
                                                   const float* __restrict__ b2a,
                                                   const float* __restrict__ wc2,
                                                   const float* __restrict__ c0,
                                                   float* __restrict__ sbuf) {
    __shared__ float wcl[HID];
    __shared__ float b2l[HID];
    int t = threadIdx.x;
    if (t < HID) { wcl[t] = wc2[t]; b2l[t] = b2a[t]; }
    __syncthreads();

    int sub = t >> 5;
    int f = t & 31;
    int n = blockIdx.x * 8 + sub;
    size_t ix = (size_t)n * 32 + f;

    float u = bf2f(p0[ix]) + bf2f(p1[ix]) + bf2f(yself[ix]) + b2l[f];
    u = u > 0.f ? u : 0.f;
    float tt = u * wcl[f];
    #pragma unroll
    for (int off = 16; off > 0; off >>= 1) tt += __shfl_xor(tt, off, 32);
    if (f == 0) sbuf[n] = tt + *c0;
}

// ---------------- layer3: scalar aggregate (sbuf L2-resident, esrc nt) ----------------
__global__ __launch_bounds__(256) void final_kernel(const float* __restrict__ sbuf,
                                                    const int* __restrict__ rowbeg,
                                                    const int* __restrict__ rowend,
                                                    const int* __restrict__ esrc,
                                                    const float* __restrict__ b3,
                                                    float* __restrict__ out) {
    int n = blockIdx.x * 256 + threadIdx.x;
    if (n >= NN) return;
    float v = sbuf[n] + b3[0];
    int beg = rowbeg[n], end = rowend[n];
    int p = beg;
    for (; p + 4 <= end; p += 4) {
        int s0 = __builtin_nontemporal_load(&esrc[p]);
        int s1 = __builtin_nontemporal_load(&esrc[p + 1]);
        int s2 = __builtin_nontemporal_load(&esrc[p + 2]);
        int s3 = __builtin_nontemporal_load(&esrc[p + 3]);
        float g0 = sbuf[s0], g1 = sbuf[s1], g2 = sbuf[s2], g3 = sbuf[s3];
        v += g0; v += g1; v += g2; v += g3;
    }
    for (; p < end; p++) v += sbuf[__builtin_nontemporal_load(&esrc[p])];
    out[n] = v;
}

// ---------------- host ----------------
extern "C" void kernel_launch(void* const* d_in, const int* in_sizes, int n_in,
                              void* d_out, int out_size, void* d_ws, size_t ws_size,
                              hipStream_t stream) {
    const float* x   = (const float*)d_in[0];
    const void*  ei  = d_in[1];
    const float* w1a = (const float*)d_in[2];
    const float* b1a = (const float*)d_in[3];
    const float* w1b = (const float*)d_in[4];
    const float* b1b = (const float*)d_in[5];
    const float* w2a = (const float*)d_in[6];
    const float* b2a = (const float*)d_in[7];
    const float* w2b = (const float*)d_in[8];
    const float* b2b = (const float*)d_in[9];
    const float* w3  = (const float*)d_in[10];
    const float* b3  = (const float*)d_in[11];
    float* out = (float*)d_out;

    char* w = (char*)d_ws;
    ushort_t*     y1      = (ushort_t*)(w + 0);             //  6,400,000
    ushort_t*     y2      = (ushort_t*)(w + 6400000);       //  6,400,000
    int*          esrc    = (int*)     (w + 12800000);      //  8,007,680 (NB*BCAP*4)
    int*          rowbeg  = (int*)     (w + 20807680);      //    400,000
    int*          rowmid  = (int*)     (w + 21207680);      //    400,000
    int*          rowend  = (int*)     (w + 21607680);      //    400,000
    float*        sbuf    = (float*)   (w + 22007680);      //    400,000
    int*          gcursor = (int*)     (w + 22407680);      //      3,136
    int*          flag    = (int*)     (w + 22410816);      //         16
    float*        Wc      = (float*)   (w + 22410832);      //      4,096
    float*        bc1     = (float*)   (w + 22414928);      //        128
    float*        wc2     = (float*)   (w + 22415056);      //        128
    float*        c0      = (float*)   (w + 22415184);      //         48 -> pad 22415232
    // binned (8.0 MB) overlays p0/p1 (12.8 MB) — binned dead after bucket_csr
    unsigned int* binned  = (unsigned int*)(w + 22415232);  //  8,007,680
    ushort_t*     part0   = (ushort_t*)(w + 22415232);      //  6,400,000
    ushort_t*     part1   = (ushort_t*)(w + 28815232);      //  6,400,000 -> ends 35,215,232

    setup_kernel<<<2, 1024, 0, stream>>>(ei, w1b, b1b, w2a, w2b, b2b, w3,
                                         flag, gcursor, Wc, bc1, wc2, c0);
    proj_bin_kernel<<<NPJ + NBA, 256, 0, stream>>>(x, w1a, y1, ei, flag, gcursor, binned);
    bucket_csr_kernel<<<NB, 256, 0, stream>>>(binned, gcursor, rowbeg, rowmid, rowend, esrc);

    // layer 1: two L2-resident half-gathers + streaming MLP
    agg_half_kernel<<<NN / 4, 256, 0, stream>>>(y1, rowbeg, rowmid, esrc, part0);
    agg_half_kernel<<<NN / 4, 256, 0, stream>>>(y1, rowmid, rowend, esrc, part1);
    mlp1_kernel<<<NN / 8, 256, 0, stream>>>(part0, part1, y1, b1a, Wc, bc1, y2);

    // layer 2
    agg_half_kernel<<<NN / 4, 256, 0, stream>>>(y2, rowbeg, rowmid, esrc, part0);
    agg_half_kernel<<<NN / 4, 256, 0, stream>>>(y2, rowmid, rowend, esrc, part1);
    mlp2_kernel<<<NN / 8, 256, 0, stream>>>(part0, part1, y2, b2a, wc2, c0, sbuf);

    // layer 3
    final_kernel<<<(NN + 255) / 256, 256, 0, stream>>>(sbuf, rowbeg, rowend, esrc, b3, out);
}

// Round 9
// 158.955 us; speedup vs baseline: 1.6048x; 1.6048x over previous
//
#include <hip/hip_runtime.h>

#define NN 100000
#define NE 1600000
#define IC 128
#define HID 32
#define NB 782           // buckets of 128 nodes
#define BCAP 2560        // padded bucket capacity (mean 2048, sigma~45)
#define EB 4096          // edges per binning block
#define NBA 391          // ceil(NE/EB)
#define NPJ 1563         // ceil(NN/64) proj blocks

typedef unsigned short ushort_t;

__device__ __forceinline__ ushort_t f2bf(float x) {
    unsigned u = __float_as_uint(x);
    unsigned r = (u + 0x7fffu + ((u >> 16) & 1u)) >> 16;   // RNE
    return (ushort_t)r;
}
__device__ __forceinline__ float bf2f(ushort_t b) {
    return __uint_as_float(((unsigned)b) << 16);
}

__device__ __forceinline__ int edge_at(const void* ei, int i64f, long long idx) {
    return i64f ? (int)((const long long*)ei)[idx] : ((const int*)ei)[idx];
}

// ---------------- setup: detect dtype + precompute folded weights + zero cursors ----------------
__global__ __launch_bounds__(1024) void setup_kernel(const void* ei,
                                                     const float* __restrict__ w1b, const float* __restrict__ b1b,
                                                     const float* __restrict__ w2a, const float* __restrict__ w2b,
                                                     const float* __restrict__ b2b, const float* __restrict__ w3,
                                                     int* flag, int* gcursor,
                                                     float* Wc, float* bc1, float* wc2, float* c0) {
    int t = threadIdx.x;
    if (blockIdx.x == 1) {
        if (t < NB) gcursor[t] = 0;
        return;
    }
    if (t < 64) {
        const long long* p = (const long long*)ei;
        long long v = p[t];
        unsigned long long bad = __ballot(v < 0 || v >= NN);
        if (t == 0) *flag = (bad == 0ull) ? 1 : 0;
    }
    int k = t >> 5, j = t & 31;
    float acc = 0.f;
    for (int m = 0; m < HID; m++) acc += w1b[k * HID + m] * w2a[m * HID + j];
    Wc[k * HID + j] = acc;
    if (t < 32) {
        float a = 0.f;
        for (int m = 0; m < HID; m++) a += b1b[m] * w2a[m * HID + t];
        bc1[t] = a;
    } else if (t < 64) {
        int kk = t - 32;
        float a = 0.f;
        for (int jj = 0; jj < HID; jj++) a += w2b[kk * HID + jj] * w3[jj];
        wc2[kk] = a;
    } else if (t == 64) {
        float a = 0.f;
        for (int jj = 0; jj < HID; jj++) a += b2b[jj] * w3[jj];
        *c0 = a;
    }
}

// ---------------- binscatter (blocks first) + proj1 (64-node tile) merged ----------------
union SMU {
    struct { float xs[64 * 132]; float ws[IC * HID]; } pj;              // 50,176 B
    struct { int raws[EB]; int rawd[EB]; int h[NB]; int lcur[NB]; } bs; // 39,024 B
};

__global__ __launch_bounds__(256) void proj_bin_kernel(const float* __restrict__ x,
                                                       const float* __restrict__ w1a,
                                                       ushort_t* __restrict__ y1,
                                                       const void* ei, const int* flag,
                                                       int* gcursor,
                                                       unsigned int* __restrict__ binned) {
    __shared__ SMU sm;
    int t = threadIdx.x;

    if (blockIdx.x < NBA) {
        // ---- binscatter first: atomic-latency blocks start early, overlap proj ----
        int bb = blockIdx.x;
        for (int b = t; b < NB; b += 256) sm.bs.h[b] = 0;
        __syncthreads();
        int i64f = *flag;
        long long ebase = (long long)bb * EB;
        for (int i = t; i < EB; i += 256) {
            long long e = ebase + i;
            int s = 0, d = -1;
            if (e < NE) {
                s = edge_at(ei, i64f, e);
                d = edge_at(ei, i64f, NE + e);
                atomicAdd(&sm.bs.h[d >> 7], 1);
            }
            sm.bs.raws[i] = s;
            sm.bs.rawd[i] = d;
        }
        __syncthreads();
        for (int b = t; b < NB; b += 256)
            sm.bs.lcur[b] = sm.bs.h[b] ? atomicAdd(&gcursor[b], sm.bs.h[b]) : 0;
        __syncthreads();
        for (int i = t; i < EB; i += 256) {
            int d = sm.bs.rawd[i];
            if (d >= 0) {
                int b = d >> 7;
                int pos = atomicAdd(&sm.bs.lcur[b], 1);
                binned[(size_t)b * BCAP + pos] = ((unsigned)sm.bs.raws[i] << 7) | (unsigned)(d & 127);
            }
        }
    } else {
        // ---- proj1: y1 = bf16(x @ w1a), one 64B line per node row ----
        int base = (blockIdx.x - NBA) * 64;
        #pragma unroll
        for (int i = 0; i < 16; i++) sm.pj.ws[i * 256 + t] = w1a[i * 256 + t];
        const float4* xg = (const float4*)x;
        #pragma unroll
        for (int i = 0; i < 8; i++) {
            int fi = i * 256 + t;
            int row = fi >> 5;
            int kq = fi & 31;
            float4 v = make_float4(0.f, 0.f, 0.f, 0.f);
            if (base + row < NN) v = xg[(size_t)(base + row) * 32 + kq];
            *(float4*)&sm.pj.xs[row * 132 + kq * 4] = v;
        }
        __syncthreads();

        int ng = t >> 3;
        int fg = t & 7;
        int n0 = ng * 2, n1 = n0 + 1;
        int j0 = fg * 4;
        float4 a0 = make_float4(0.f, 0.f, 0.f, 0.f);
        float4 a1 = make_float4(0.f, 0.f, 0.f, 0.f);
        #pragma unroll 8
        for (int k = 0; k < IC; k++) {
            float x0 = sm.pj.xs[n0 * 132 + k];
            float x1 = sm.pj.xs[n1 * 132 + k];
            float4 w = *(const float4*)&sm.pj.ws[k * HID + j0];
            a0.x += x0 * w.x; a0.y += x0 * w.y; a0.z += x0 * w.z; a0.w += x0 * w.w;
            a1.x += x1 * w.x; a1.y += x1 * w.y; a1.z += x1 * w.z; a1.w += x1 * w.w;
        }
        ushort4 p0, p1;
        p0.x = f2bf(a0.x); p0.y = f2bf(a0.y); p0.z = f2bf(a0.z); p0.w = f2bf(a0.w);
        p1.x = f2bf(a1.x); p1.y = f2bf(a1.y); p1.z = f2bf(a1.z); p1.w = f2bf(a1.w);
        if (base + n0 < NN) *(ushort4*)&y1[(size_t)(base + n0) * 32 + j0] = p0;
        if (base + n1 < NN) *(ushort4*)&y1[(size_t)(base + n1) * 32 + j0] = p1;
    }
}

// ---------------- per-bucket CSR into padded esrc ----------------
__global__ __launch_bounds__(256) void bucket_csr_kernel(const unsigned int* __restrict__ binned,
                                                         const int* __restrict__ gcursor,
                                                         int* __restrict__ rowbeg,
                                                         int* __restrict__ rowend,
                                                         int* __restrict__ esrc) {
    __shared__ int cnt[128];
    __shared__ int sc[128];
    __shared__ int cur[128];
    int t = threadIdx.x;
    int b = blockIdx.x;
    int n = gcursor[b];
    int bbase = b * BCAP;
    if (t < 128) cnt[t] = 0;
    __syncthreads();
    for (int p = t; p < n; p += 256)
        atomicAdd(&cnt[binned[bbase + p] & 127], 1);
    __syncthreads();
    if (t < 128) sc[t] = cnt[t];
    __syncthreads();
    for (int off = 1; off < 128; off <<= 1) {
        int a = 0;
        if (t < 128 && t >= off) a = sc[t - off];
        __syncthreads();
        if (t < 128) sc[t] += a;
        __syncthreads();
    }
    if (t < 128) {
        int excl = sc[t] - cnt[t];
        int gn = (b << 7) + t;
        if (gn < NN) { rowbeg[gn] = bbase + excl; rowend[gn] = bbase + excl + cnt[t]; }
        cur[t] = excl;
    }
    __syncthreads();
    for (int p = t; p < n; p += 256) {
        unsigned w = binned[bbase + p];
        int dl = w & 127;
        int pos = bbase + atomicAdd(&cur[dl], 1);
        esrc[pos] = w >> 7;
    }
}

// ---------------- agg32: shfl-free gather-sum of bf16[n][32] rows -> fp32 agg ----------------
// 8-lane group per node (wave = 8 nodes); group walks the node's edge list serially
// with 4-way unrolled independent accumulators. lane l covers features 4l..4l+3.
__global__ __launch_bounds__(256) void agg32_kernel(const ushort_t* __restrict__ y,
                                                    const int* __restrict__ rowbeg,
                                                    const int* __restrict__ rowend,
                                                    const int* __restrict__ esrc,
                                                    float* __restrict__ agg) {
    int t = threadIdx.x;
    int g = t >> 3;           // 0..31 node group within block
    int l = t & 7;            // feature quad
    int n = blockIdx.x * 32 + g;       // NN/32 = 3125 blocks exact

    int beg = rowbeg[n], end = rowend[n];
    float ax = 0.f, ay = 0.f, az = 0.f, aw = 0.f;
    float bx = 0.f, by = 0.f, bz = 0.f, bw = 0.f;
    float cx = 0.f, cy = 0.f, cz = 0.f, cw = 0.f;
    float dx = 0.f, dy = 0.f, dz = 0.f, dw = 0.f;
    int p = beg;
    for (; p + 4 <= end; p += 4) {
        int s0 = esrc[p];
        int s1 = esrc[p + 1];
        int s2 = esrc[p + 2];
        int s3 = esrc[p + 3];
        ushort4 u0 = *(const ushort4*)&y[(size_t)s0 * 32 + l * 4];
        ushort4 u1 = *(const ushort4*)&y[(size_t)s1 * 32 + l * 4];
        ushort4 u2 = *(const ushort4*)&y[(size_t)s2 * 32 + l * 4];
        ushort4 u3 = *(const ushort4*)&y[(size_t)s3 * 32 + l * 4];
        ax += bf2f(u0.x); ay += bf2f(u0.y); az += bf2f(u0.z); aw += bf2f(u0.w);
        bx += bf2f(u1.x); by += bf2f(u1.y); bz += bf2f(u1.z); bw += bf2f(u1.w);
        cx += bf2f(u2.x); cy += bf2f(u2.y); cz += bf2f(u2.z); cw += bf2f(u2.w);
        dx += bf2f(u3.x); dy += bf2f(u3.y); dz += bf2f(u3.z); dw += bf2f(u3.w);
    }
    for (; p < end; p++) {
        ushort4 u0 = *(const ushort4*)&y[(size_t)esrc[p] * 32 + l * 4];
        ax += bf2f(u0.x); ay += bf2f(u0.y); az += bf2f(u0.z); aw += bf2f(u0.w);
    }
    ushort4 us = *(const ushort4*)&y[(size_t)n * 32 + l * 4];   // self (eps=0)
    float4 o;
    o.x = (ax + bx) + (cx + dx) + bf2f(us.x);
    o.y = (ay + by) + (cy + dy) + bf2f(us.y);
    o.z = (az + bz) + (cz + dz) + bf2f(us.z);
    o.w = (aw + bw) + (cw + dw) + bf2f(us.w);
    *(float4*)&agg[(size_t)n * 32 + l * 4] = o;
}

// ---------------- mlp1: y2 = relu(agg + b1a) @ Wc + bc1 -> bf16[n][32] ----------------
__global__ __launch_bounds__(256) void mlp1_kernel(const float* __restrict__ agg,
                                                   const float* __restrict__ b1a,
                                                   const float* __restrict__ Wc,
                                                   const float* __restrict__ bc1,
                                                   ushort_t* __restrict__ y2) {
    __shared__ float Wl[HID * HID];
    __shared__ float b1l[HID];
    __shared__ float bcl[HID];
    int t = threadIdx.x;
    #pragma unroll
    for (int i = 0; i < 4; i++) Wl[i * 256 + t] = Wc[i * 256 + t];
    if (t < HID) { b1l[t] = b1a[t]; bcl[t] = bc1[t]; }
    __syncthreads();

    int sub = t >> 5;
    int f = t & 31;
    int n = blockIdx.x * 8 + sub;      // NN divisible by 8

    float u = agg[(size_t)n * 32 + f] + b1l[f];
    u = u > 0.f ? u : 0.f;
    float o = bcl[f];
    #pragma unroll
    for (int k = 0; k < HID; k++)
        o += __shfl(u, k, 32) * Wl[k * HID + f];

    y2[(size_t)n * 32 + f] = f2bf(o);
}

// ---------------- mlp2: s = relu(agg + b2a) . wc2 + c0 ----------------
__global__ __launch_bounds__(256) void mlp2_kernel(const float* __restrict__ agg,
                                                   const float* __restrict__ b2a,
                                                   const float* __restrict__ wc2,
                                                   const float* __restrict__ c0,
                                                   float* __restrict__ sbuf) {
    __shared__ float wcl[HID];
    __shared__ float b2l[HID];
    int t = threadIdx.x;
    if (t < HID) { wcl[t] = wc2[t]; b2l[t] = b2a[t]; }
    __syncthreads();

    int sub = t >> 5;
    int f = t & 31;
    int n = blockIdx.x * 8 + sub;

    float u = agg[(size_t)n * 32 + f] + b2l[f];
    u = u > 0.f ? u : 0.f;
    float tt = u * wcl[f];
    #pragma unroll
    for (int off = 16; off > 0; off >>= 1) tt += __shfl_xor(tt, off, 32);
    if (f == 0) sbuf[n] = tt + *c0;
}

// ---------------- layer3: scalar aggregate ----------------
__global__ __launch_bounds__(256) void final_kernel(const float* __restrict__ sbuf,
                                                    const int* __restrict__ rowbeg,
                                                    const int* __restrict__ rowend,
                                                    const int* __restrict__ esrc,
                                                    const float* __restrict__ b3,
                                                    float* __restrict__ out) {
    int n = blockIdx.x * 256 + threadIdx.x;
    if (n >= NN) return;
    float v = sbuf[n] + b3[0];
    int beg = rowbeg[n], end = rowend[n];
    int p = beg;
    for (; p + 4 <= end; p += 4) {
        int s0 = esrc[p], s1 = esrc[p + 1], s2 = esrc[p + 2], s3 = esrc[p + 3];
        float g0 = sbuf[s0], g1 = sbuf[s1], g2 = sbuf[s2], g3 = sbuf[s3];
        v += g0; v += g1; v += g2; v += g3;
    }
    for (; p < end; p++) v += sbuf[esrc[p]];
    out[n] = v;
}

// ---------------- host ----------------
extern "C" void kernel_launch(void* const* d_in, const int* in_sizes, int n_in,
                              void* d_out, int out_size, void* d_ws, size_t ws_size,
                              hipStream_t stream) {
    const float* x   = (const float*)d_in[0];
    const void*  ei  = d_in[1];
    const float* w1a = (const float*)d_in[2];
    const float* b1a = (const float*)d_in[3];
    const float* w1b = (const float*)d_in[4];
    const float* b1b = (const float*)d_in[5];
    const float* w2a = (const float*)d_in[6];
    const float* b2a = (const float*)d_in[7];
    const float* w2b = (const float*)d_in[8];
    const float* b2b = (const float*)d_in[9];
    const float* w3  = (const float*)d_in[10];
    const float* b3  = (const float*)d_in[11];
    float* out = (float*)d_out;

    char* w = (char*)d_ws;
    ushort_t*     y1      = (ushort_t*)(w + 0);             //  6,400,000
    ushort_t*     y2      = (ushort_t*)(w + 6400000);       //  6,400,000
    int*          esrc    = (int*)     (w + 12800000);      //  8,007,680 (NB*BCAP*4)
    int*          rowbeg  = (int*)     (w + 20807680);      //    400,000
    int*          rowend  = (int*)     (w + 21207680);      //    400,000
    float*        sbuf    = (float*)   (w + 21607680);      //    400,000
    int*          gcursor = (int*)     (w + 22007680);      //      3,136
    int*          flag    = (int*)     (w + 22010816);      //         16
    float*        Wc      = (float*)   (w + 22010832);      //      4,096
    float*        bc1     = (float*)   (w + 22014928);      //        128
    float*        wc2     = (float*)   (w + 22015056);      //        128
    float*        c0      = (float*)   (w + 22015184);      //         48 (pad to 22015232)
    // binned (8.0 MB) overlays agg (12.8 MB fp32) — binned dead after bucket_csr
    unsigned int* binned  = (unsigned int*)(w + 22015232);
    float*        agg     = (float*)      (w + 22015232);   // ends at 34,815,232

    setup_kernel<<<2, 1024, 0, stream>>>(ei, w1b, b1b, w2a, w2b, b2b, w3,
                                         flag, gcursor, Wc, bc1, wc2, c0);
    proj_bin_kernel<<<NBA + NPJ, 256, 0, stream>>>(x, w1a, y1, ei, flag, gcursor, binned);
    bucket_csr_kernel<<<NB, 256, 0, stream>>>(binned, gcursor, rowbeg, rowend, esrc);

    agg32_kernel<<<NN / 32, 256, 0, stream>>>(y1, rowbeg, rowend, esrc, agg);
    mlp1_kernel<<<NN / 8, 256, 0, stream>>>(agg, b1a, Wc, bc1, y2);

    agg32_kernel<<<NN / 32, 256, 0, stream>>>(y2, rowbeg, rowend, esrc, agg);
    mlp2_kernel<<<NN / 8, 256, 0, stream>>>(agg, b2a, wc2, c0, sbuf);

    final_kernel<<<(NN + 255) / 256, 256, 0, stream>>>(sbuf, rowbeg, rowend, esrc, b3, out);
}

// Round 10
// 144.944 us; speedup vs baseline: 1.7599x; 1.0967x over previous
//
#include <hip/hip_runtime.h>

#define NN 100000
#define NE 1600000
#define IC 128
#define HID 32
#define NB 782           // buckets of 128 nodes
#define BCAP 2560        // padded bucket capacity (mean 2048, sigma~45)
#define EB 4096          // edges per binning block
#define NBA 391          // ceil(NE/EB)
#define NPJ 1563         // ceil(NN/64) proj blocks (64 nodes each)

typedef unsigned short ushort_t;
typedef __attribute__((ext_vector_type(8))) short short8v;
typedef __attribute__((ext_vector_type(4))) float f32x4;

__device__ __forceinline__ ushort_t f2bf(float x) {
    unsigned u = __float_as_uint(x);
    unsigned r = (u + 0x7fffu + ((u >> 16) & 1u)) >> 16;   // RNE
    return (ushort_t)r;
}
__device__ __forceinline__ float bf2f(ushort_t b) {
    return __uint_as_float(((unsigned)b) << 16);
}

__device__ __forceinline__ int edge_at(const void* ei, int i64f, long long idx) {
    return i64f ? (int)((const long long*)ei)[idx] : ((const int*)ei)[idx];
}

// ---------------- setup: detect + folded weights + cursors + w1a MFMA B-fragments ----------------
// Bfrag[s][u][l][j] = bf16(w1a[(s*32 + (l>>4)*8 + j)*32 + u*16 + (l&15)])
__global__ __launch_bounds__(1024) void setup_kernel(const void* ei, const float* __restrict__ w1a,
                                                     const float* __restrict__ w1b, const float* __restrict__ b1b,
                                                     const float* __restrict__ w2a, const float* __restrict__ w2b,
                                                     const float* __restrict__ b2b, const float* __restrict__ w3,
                                                     int* flag, int* gcursor,
                                                     float* Wc, float* bc1, float* wc2, float* c0,
                                                     ushort_t* Bfrag) {
    int t = threadIdx.x;
    if (blockIdx.x == 1) {
        if (t < NB) gcursor[t] = 0;
        return;
    }
    if (blockIdx.x == 2) {
        if (t < 512) {
            int s = t >> 7, u = (t >> 6) & 1, l = t & 63;
            int krow = s * 32 + (l >> 4) * 8;
            int col = u * 16 + (l & 15);
            #pragma unroll
            for (int j = 0; j < 8; j++)
                Bfrag[t * 8 + j] = f2bf(w1a[(krow + j) * 32 + col]);
        }
        return;
    }
    if (t < 64) {
        const long long* p = (const long long*)ei;
        long long v = p[t];
        unsigned long long bad = __ballot(v < 0 || v >= NN);
        if (t == 0) *flag = (bad == 0ull) ? 1 : 0;
    }
    int k = t >> 5, j = t & 31;
    float acc = 0.f;
    for (int m = 0; m < HID; m++) acc += w1b[k * HID + m] * w2a[m * HID + j];
    Wc[k * HID + j] = acc;
    if (t < 32) {
        float a = 0.f;
        for (int m = 0; m < HID; m++) a += b1b[m] * w2a[m * HID + t];
        bc1[t] = a;
    } else if (t < 64) {
        int kk = t - 32;
        float a = 0.f;
        for (int jj = 0; jj < HID; jj++) a += w2b[kk * HID + jj] * w3[jj];
        wc2[kk] = a;
    } else if (t == 64) {
        float a = 0.f;
        for (int jj = 0; jj < HID; jj++) a += b2b[jj] * w3[jj];
        *c0 = a;
    }
}

// ---------------- binscatter (blocks first) + MFMA proj merged ----------------
__global__ __launch_bounds__(256) void proj_bin_kernel(const float* __restrict__ x,
                                                       const ushort_t* __restrict__ Bfrag,
                                                       ushort_t* __restrict__ y1,
                                                       const void* ei, const int* flag,
                                                       int* gcursor,
                                                       unsigned int* __restrict__ binned) {
    __shared__ int raws[EB];
    __shared__ int rawd[EB];
    __shared__ int hh[NB];
    __shared__ int lcur[NB];
    int t = threadIdx.x;

    if (blockIdx.x < NBA) {
        // ---- binscatter: atomic-latency blocks start early, overlap proj ----
        int bb = blockIdx.x;
        for (int b = t; b < NB; b += 256) hh[b] = 0;
        __syncthreads();
        int i64f = *flag;
        long long ebase = (long long)bb * EB;
        for (int i = t; i < EB; i += 256) {
            long long e = ebase + i;
            int s = 0, d = -1;
            if (e < NE) {
                s = edge_at(ei, i64f, e);
                d = edge_at(ei, i64f, NE + e);
                atomicAdd(&hh[d >> 7], 1);
            }
            raws[i] = s;
            rawd[i] = d;
        }
        __syncthreads();
        for (int b = t; b < NB; b += 256)
            lcur[b] = hh[b] ? atomicAdd(&gcursor[b], hh[b]) : 0;
        __syncthreads();
        for (int i = t; i < EB; i += 256) {
            int d = rawd[i];
            if (d >= 0) {
                int b = d >> 7;
                int pos = atomicAdd(&lcur[b], 1);
                binned[(size_t)b * BCAP + pos] = ((unsigned)raws[i] << 7) | (unsigned)(d & 127);
            }
        }
    } else {
        // ---- MFMA proj: y1 = bf16(x @ w1a). 4 waves x 16 nodes, no LDS ----
        int pb = blockIdx.x - NBA;
        int wv = t >> 6, l = t & 63;
        int base = pb * 64 + wv * 16;
        int row = l & 15;
        int kg = l >> 4;                 // 0..3
        size_t m = (size_t)(base + row);
        if (m >= NN) m = NN - 1;         // clamp (last block): result discarded
        const float* xr = x + m * 128 + kg * 8;

        f32x4 acc0 = {0.f, 0.f, 0.f, 0.f};
        f32x4 acc1 = {0.f, 0.f, 0.f, 0.f};
        #pragma unroll
        for (int s = 0; s < 4; s++) {
            float4 xa = *(const float4*)(xr + s * 32);
            float4 xb = *(const float4*)(xr + s * 32 + 4);
            short8v af;
            af[0] = (short)f2bf(xa.x); af[1] = (short)f2bf(xa.y);
            af[2] = (short)f2bf(xa.z); af[3] = (short)f2bf(xa.w);
            af[4] = (short)f2bf(xb.x); af[5] = (short)f2bf(xb.y);
            af[6] = (short)f2bf(xb.z); af[7] = (short)f2bf(xb.w);
            short8v b0 = *(const short8v*)&Bfrag[((s * 2 + 0) * 64 + l) * 8];
            short8v b1 = *(const short8v*)&Bfrag[((s * 2 + 1) * 64 + l) * 8];
            acc0 = __builtin_amdgcn_mfma_f32_16x16x32_bf16(af, b0, acc0, 0, 0, 0);
            acc1 = __builtin_amdgcn_mfma_f32_16x16x32_bf16(af, b1, acc1, 0, 0, 0);
        }
        // D: col = l&15, row = (l>>4)*4 + reg   [m89 verified]
        int col = l & 15;
        #pragma unroll
        for (int r = 0; r < 4; r++) {
            int node = base + kg * 4 + r;
            if (node < NN) {
                y1[(size_t)node * 32 + col]      = f2bf(acc0[r]);
                y1[(size_t)node * 32 + 16 + col] = f2bf(acc1[r]);
            }
        }
    }
}

// ---------------- per-bucket CSR into padded esrc ----------------
__global__ __launch_bounds__(256) void bucket_csr_kernel(const unsigned int* __restrict__ binned,
                                                         const int* __restrict__ gcursor,
                                                         int* __restrict__ rowbeg,
                                                         int* __restrict__ rowend,
                                                         int* __restrict__ esrc) {
    __shared__ int cnt[128];
    __shared__ int sc[128];
    __shared__ int cur[128];
    int t = threadIdx.x;
    int b = blockIdx.x;
    int n = gcursor[b];
    int bbase = b * BCAP;
    if (t < 128) cnt[t] = 0;
    __syncthreads();
    for (int p = t; p < n; p += 256)
        atomicAdd(&cnt[binned[bbase + p] & 127], 1);
    __syncthreads();
    if (t < 128) sc[t] = cnt[t];
    __syncthreads();
    for (int off = 1; off < 128; off <<= 1) {
        int a = 0;
        if (t < 128 && t >= off) a = sc[t - off];
        __syncthreads();
        if (t < 128) sc[t] += a;
        __syncthreads();
    }
    if (t < 128) {
        int excl = sc[t] - cnt[t];
        int gn = (b << 7) + t;
        if (gn < NN) { rowbeg[gn] = bbase + excl; rowend[gn] = bbase + excl + cnt[t]; }
        cur[t] = excl;
    }
    __syncthreads();
    for (int p = t; p < n; p += 256) {
        unsigned w = binned[bbase + p];
        int dl = w & 127;
        int pos = bbase + atomicAdd(&cur[dl], 1);
        esrc[pos] = w >> 7;
    }
}

// ---------------- agg32: shfl-free gather-sum of bf16[n][32] rows -> fp32 agg ----------------
__global__ __launch_bounds__(256) void agg32_kernel(const ushort_t* __restrict__ y,
                                                    const int* __restrict__ rowbeg,
                                                    const int* __restrict__ rowend,
                                                    const int* __restrict__ esrc,
                                                    float* __restrict__ agg) {
    int t = threadIdx.x;
    int g = t >> 3;           // 0..31 node group within block
    int l = t & 7;            // feature quad
    int n = blockIdx.x * 32 + g;       // NN/32 = 3125 blocks exact

    int beg = rowbeg[n], end = rowend[n];
    float ax = 0.f, ay = 0.f, az = 0.f, aw = 0.f;
    float bx = 0.f, by = 0.f, bz = 0.f, bw = 0.f;
    float cx = 0.f, cy = 0.f, cz = 0.f, cw = 0.f;
    float dx = 0.f, dy = 0.f, dz = 0.f, dw = 0.f;
    int p = beg;
    for (; p + 4 <= end; p += 4) {
        int s0 = esrc[p];
        int s1 = esrc[p + 1];
        int s2 = esrc[p + 2];
        int s3 = esrc[p + 3];
        ushort4 u0 = *(const ushort4*)&y[(size_t)s0 * 32 + l * 4];
        ushort4 u1 = *(const ushort4*)&y[(size_t)s1 * 32 + l * 4];
        ushort4 u2 = *(const ushort4*)&y[(size_t)s2 * 32 + l * 4];
        ushort4 u3 = *(const ushort4*)&y[(size_t)s3 * 32 + l * 4];
        ax += bf2f(u0.x); ay += bf2f(u0.y); az += bf2f(u0.z); aw += bf2f(u0.w);
        bx += bf2f(u1.x); by += bf2f(u1.y); bz += bf2f(u1.z); bw += bf2f(u1.w);
        cx += bf2f(u2.x); cy += bf2f(u2.y); cz += bf2f(u2.z); cw += bf2f(u2.w);
        dx += bf2f(u3.x); dy += bf2f(u3.y); dz += bf2f(u3.z); dw += bf2f(u3.w);
    }
    for (; p < end; p++) {
        ushort4 u0 = *(const ushort4*)&y[(size_t)esrc[p] * 32 + l * 4];
        ax += bf2f(u0.x); ay += bf2f(u0.y); az += bf2f(u0.z); aw += bf2f(u0.w);
    }
    ushort4 us = *(const ushort4*)&y[(size_t)n * 32 + l * 4];   // self (eps=0)
    float4 o;
    o.x = (ax + bx) + (cx + dx) + bf2f(us.x);
    o.y = (ay + by) + (cy + dy) + bf2f(us.y);
    o.z = (az + bz) + (cz + dz) + bf2f(us.z);
    o.w = (aw + bw) + (cw + dw) + bf2f(us.w);
    *(float4*)&agg[(size_t)n * 32 + l * 4] = o;
}

// ---------------- mlp1: y2 = relu(agg + b1a) @ Wc + bc1 -> bf16[n][32] ----------------
__global__ __launch_bounds__(256) void mlp1_kernel(const float* __restrict__ agg,
                                                   const float* __restrict__ b1a,
                                                   const float* __restrict__ Wc,
                                                   const float* __restrict__ bc1,
                                                   ushort_t* __restrict__ y2) {
    __shared__ float Wl[HID * HID];
    __shared__ float b1l[HID];
    __shared__ float bcl[HID];
    int t = threadIdx.x;
    #pragma unroll
    for (int i = 0; i < 4; i++) Wl[i * 256 + t] = Wc[i * 256 + t];
    if (t < HID) { b1l[t] = b1a[t]; bcl[t] = bc1[t]; }
    __syncthreads();

    int sub = t >> 5;
    int f = t & 31;
    int n = blockIdx.x * 8 + sub;      // NN divisible by 8

    float u = agg[(size_t)n * 32 + f] + b1l[f];
    u = u > 0.f ? u : 0.f;
    float o = bcl[f];
    #pragma unroll
    for (int k = 0; k < HID; k++)
        o += __shfl(u, k, 32) * Wl[k * HID + f];

    y2[(size_t)n * 32 + f] = f2bf(o);
}

// ---------------- mlp2: s = relu(agg + b2a) . wc2 + c0 ----------------
__global__ __launch_bounds__(256) void mlp2_kernel(const float* __restrict__ agg,
                                                   const float* __restrict__ b2a,
                                                   const float* __restrict__ wc2,
                                                   const float* __restrict__ c0,
                                                   float* __restrict__ sbuf) {
    __shared__ float wcl[HID];
    __shared__ float b2l[HID];
    int t = threadIdx.x;
    if (t < HID) { wcl[t] = wc2[t]; b2l[t] = b2a[t]; }
    __syncthreads();

    int sub = t >> 5;
    int f = t & 31;
    int n = blockIdx.x * 8 + sub;

    float u = agg[(size_t)n * 32 + f] + b2l[f];
    u = u > 0.f ? u : 0.f;
    float tt = u * wcl[f];
    #pragma unroll
    for (int off = 16; off > 0; off >>= 1) tt += __shfl_xor(tt, off, 32);
    if (f == 0) sbuf[n] = tt + *c0;
}

// ---------------- layer3: scalar aggregate ----------------
__global__ __launch_bounds__(256) void final_kernel(const float* __restrict__ sbuf,
                                                    const int* __restrict__ rowbeg,
                                                    const int* __restrict__ rowend,
                                                    const int* __restrict__ esrc,
                                                    const float* __restrict__ b3,
                                                    float* __restrict__ out) {
    int n = blockIdx.x * 256 + threadIdx.x;
    if (n >= NN) return;
    float v = sbuf[n] + b3[0];
    int beg = rowbeg[n], end = rowend[n];
    int p = beg;
    for (; p + 4 <= end; p += 4) {
        int s0 = esrc[p], s1 = esrc[p + 1], s2 = esrc[p + 2], s3 = esrc[p + 3];
        float g0 = sbuf[s0], g1 = sbuf[s1], g2 = sbuf[s2], g3 = sbuf[s3];
        v += g0; v += g1; v += g2; v += g3;
    }
    for (; p < end; p++) v += sbuf[esrc[p]];
    out[n] = v;
}

// ---------------- host ----------------
extern "C" void kernel_launch(void* const* d_in, const int* in_sizes, int n_in,
                              void* d_out, int out_size, void* d_ws, size_t ws_size,
                              hipStream_t stream) {
    const float* x   = (const float*)d_in[0];
    const void*  ei  = d_in[1];
    const float* w1a = (const float*)d_in[2];
    const float* b1a = (const float*)d_in[3];
    const float* w1b = (const float*)d_in[4];
    const float* b1b = (const float*)d_in[5];
    const float* w2a = (const float*)d_in[6];
    const float* b2a = (const float*)d_in[7];
    const float* w2b = (const float*)d_in[8];
    const float* b2b = (const float*)d_in[9];
    const float* w3  = (const float*)d_in[10];
    const float* b3  = (const float*)d_in[11];
    float* out = (float*)d_out;

    char* w = (char*)d_ws;
    ushort_t*     y1      = (ushort_t*)(w + 0);             //  6,400,000
    ushort_t*     y2      = (ushort_t*)(w + 6400000);       //  6,400,000
    int*          esrc    = (int*)     (w + 12800000);      //  8,007,680 (NB*BCAP*4)
    int*          rowbeg  = (int*)     (w + 20807680);      //    400,000
    int*          rowend  = (int*)     (w + 21207680);      //    400,000
    float*        sbuf    = (float*)   (w + 21607680);      //    400,000
    int*          gcursor = (int*)     (w + 22007680);      //      3,136
    int*          flag    = (int*)     (w + 22010816);      //         16
    float*        Wc      = (float*)   (w + 22010832);      //      4,096
    float*        bc1     = (float*)   (w + 22014928);      //        128
    float*        wc2     = (float*)   (w + 22015056);      //        128
    float*        c0      = (float*)   (w + 22015184);      //         48 (pad to 22015232)
    // binned (8.0 MB) overlays agg (12.8 MB fp32) — binned dead after bucket_csr
    unsigned int* binned  = (unsigned int*)(w + 22015232);
    float*        agg     = (float*)      (w + 22015232);   // ends at 34,815,232
    ushort_t*     Bfrag   = (ushort_t*)(w + 34815232);      //      8,192 -> ends 34,823,424

    setup_kernel<<<3, 1024, 0, stream>>>(ei, w1a, w1b, b1b, w2a, w2b, b2b, w3,
                                         flag, gcursor, Wc, bc1, wc2, c0, Bfrag);
    proj_bin_kernel<<<NBA + NPJ, 256, 0, stream>>>(x, Bfrag, y1, ei, flag, gcursor, binned);
    bucket_csr_kernel<<<NB, 256, 0, stream>>>(binned, gcursor, rowbeg, rowend, esrc);

    agg32_kernel<<<NN / 32, 256, 0, stream>>>(y1, rowbeg, rowend, esrc, agg);
    mlp1_kernel<<<NN / 8, 256, 0, stream>>>(agg, b1a, Wc, bc1, y2);

    agg32_kernel<<<NN / 32, 256, 0, stream>>>(y2, rowbeg, rowend, esrc, agg);
    mlp2_kernel<<<NN / 8, 256, 0, stream>>>(agg, b2a, wc2, c0, sbuf);

    final_kernel<<<(NN + 255) / 256, 256, 0, stream>>>(sbuf, rowbeg, rowend, esrc, b3, out);
}